// Round 9
// baseline (171.688 us; speedup 1.0000x reference)
//
#include <hip/hip_runtime.h>
#include <hip/hip_bf16.h>
#include <stdint.h>
#include <type_traits>

#define BS 4
#define LEN 5440
#define ROWS (BS * LEN)     // 21760 = 340 * 64

typedef __bf16 bf16;
typedef _Float16 f16;
typedef __bf16 bf16x2 __attribute__((ext_vector_type(2)));
typedef __bf16 bf16x4 __attribute__((ext_vector_type(4)));
typedef __bf16 bf16x8 __attribute__((ext_vector_type(8)));
typedef _Float16 f16x8 __attribute__((ext_vector_type(8)));
typedef float f32x4 __attribute__((ext_vector_type(4)));

// ---------------------------------------------------------------------------
// Weight prep: 64x64 LDS transpose -> bf16 weights in MFMA-fragment order:
// chunk for (col c, k-chunk kc) at ((c>>4)*32 + kc)*16 + (c&15). 57 blocks.
// ---------------------------------------------------------------------------
__global__ __launch_bounds__(256) void prep_weights(
    const float* __restrict__ vproj_w, const float* __restrict__ off_w,
    const float* __restrict__ attn_w, const float* __restrict__ out_w,
    const float* __restrict__ off_b, const float* __restrict__ attn_b,
    bf16* __restrict__ bt_v, bf16* __restrict__ bt_oa, bf16* __restrict__ bt_out,
    float* __restrict__ bias_oa)
{
    const int blk = blockIdx.x;
    const int t = threadIdx.x;
    if (blk == 56) {
        bias_oa[t] = off_b[t];
        if (t < 128) bias_oa[256 + t] = attn_b[t];
        return;
    }
    const float* W; bf16* BT; int N, tn, tk, cbase;
    if (blk < 16)      { W = vproj_w; BT = bt_v;   N = 256; tk = blk >> 2;        tn = blk & 3;        cbase = 0; }
    else if (blk < 32) { W = off_w;   BT = bt_oa;  N = 256; tk = (blk - 16) >> 2; tn = (blk - 16) & 3; cbase = 0; }
    else if (blk < 40) { W = attn_w;  BT = bt_oa;  N = 128; tk = (blk - 32) >> 1; tn = (blk - 32) & 1; cbase = 256; }
    else               { W = out_w;   BT = bt_out; N = 256; tk = (blk - 40) >> 2; tn = (blk - 40) & 3; cbase = 0; }
    const int k0 = tk * 64, n0 = tn * 64;

    __shared__ float sT[64][65];
    const int r = t >> 2;
    const int cs = (t & 3) * 16;
    const float* src = W + (size_t)(k0 + r) * N + n0 + cs;
#pragma unroll
    for (int i = 0; i < 4; ++i) {
        float4 a = *(const float4*)(src + i * 4);
        sT[r][cs + i * 4 + 0] = a.x; sT[r][cs + i * 4 + 1] = a.y;
        sT[r][cs + i * 4 + 2] = a.z; sT[r][cs + i * 4 + 3] = a.w;
    }
    __syncthreads();
    const int c = cbase + n0 + r;
    const int ng = c >> 4, cl = c & 15;
    const int kc0 = (k0 + cs) >> 3;
    bf16x8 o0, o1;
#pragma unroll
    for (int i = 0; i < 8; ++i) o0[i] = (bf16)sT[cs + i][r];
#pragma unroll
    for (int i = 0; i < 8; ++i) o1[i] = (bf16)sT[cs + 8 + i][r];
    *(bf16x8*)(BT + (size_t)(((ng * 32 + kc0) * 16 + cl) * 8)) = o0;
    *(bf16x8*)(BT + (size_t)(((ng * 32 + kc0 + 1) * 16 + cl) * 8)) = o1;
}

// ---------------------------------------------------------------------------
// GEMM stripe body: ONE 64-row m-stripe of A staged to LDS once (coalesced,
// chunk-XOR swizzled), then NB n-blocks of 128 cols processed in a loop.
// B fragments loaded coalesced from fragment-ordered global per n-block.
// HM (head-major) epilogue writes v as [b][h][pos][32] f16.
// ---------------------------------------------------------------------------
template <typename AT, int NB, typename OutT, bool HM>
__device__ __forceinline__ void gemm_stripe(
    const AT* __restrict__ A, const bf16* __restrict__ BF,
    const float* __restrict__ bias, OutT* __restrict__ C,
    int N, int m0, int tid)
{
    __shared__ bf16 sA[64 * 256];   // 32 KB

    const int wave = tid >> 6;
    const int lane = tid & 63;
    const int l15  = lane & 15;
    const int quad = lane >> 4;

    if constexpr (std::is_same_v<AT, float>) {
#pragma unroll
        for (int it = 0; it < 16; ++it) {
            const int R = wave * 16 + it;
            float4 f = *(const float4*)(A + (size_t)(m0 + R) * 256 + lane * 4);
            bf16x4 h = {(bf16)f.x, (bf16)f.y, (bf16)f.z, (bf16)f.w};
            const int ch = lane >> 1, half = lane & 1;
            *(bf16x4*)(sA + R * 256 + ((ch ^ (R & 7)) << 3) + (half << 2)) = h;
        }
    } else {
#pragma unroll
        for (int it = 0; it < 8; ++it) {
            const int R = wave * 16 + it * 2 + (lane >> 5);
            const int ch = lane & 31;
            bf16x8 h = *(const bf16x8*)(A + (size_t)(m0 + R) * 256 + ch * 8);
            *(bf16x8*)(sA + R * 256 + ((ch ^ (R & 7)) << 3)) = h;
        }
    }
    __syncthreads();

    const int b_batch = HM ? (m0 / LEN) : 0;
    const int pos0 = HM ? (m0 - b_batch * LEN) : 0;

#pragma unroll
    for (int nb = 0; nb < NB; ++nb) {
        const int ng0 = nb * 8 + wave * 2;
        bf16x8 bfr[2][8];
#pragma unroll
        for (int nt = 0; nt < 2; ++nt) {
            const bf16* bp = BF + (size_t)(ng0 + nt) * 4096 + lane * 8;
#pragma unroll
            for (int ki = 0; ki < 8; ++ki)
                bfr[nt][ki] = *(const bf16x8*)(bp + ki * 512);
        }

        f32x4 acc[4][2] = {};
#pragma unroll
        for (int mt = 0; mt < 4; ++mt) {
            const int R = mt * 16 + l15;
            const bf16* ab = sA + R * 256;
            const int sw = R & 7;
            bf16x8 afr[8];
#pragma unroll
            for (int ki = 0; ki < 8; ++ki)
                afr[ki] = *(const bf16x8*)(ab + (((ki * 4 + quad) ^ sw) << 3));
#pragma unroll
            for (int ki = 0; ki < 8; ++ki) {
#pragma unroll
                for (int nt = 0; nt < 2; ++nt)
                    acc[mt][nt] = __builtin_amdgcn_mfma_f32_16x16x32_bf16(
                        afr[ki], bfr[nt][ki], acc[mt][nt], 0, 0, 0);
            }
        }

#pragma unroll
        for (int mt = 0; mt < 4; ++mt) {
#pragma unroll
            for (int nt = 0; nt < 2; ++nt) {
                const int col = nb * 128 + wave * 32 + nt * 16 + l15;
                const float bv = bias[col];
#pragma unroll
                for (int r = 0; r < 4; ++r) {
                    const float val = acc[mt][nt][r] + bv;
                    if constexpr (HM) {
                        const int pos = pos0 + mt * 16 + (quad << 2) + r;
                        const int h = col >> 5, cc = col & 31;
                        C[(uint32_t)(((b_batch * 8 + h) * LEN + pos) * 32 + cc)]
                            = static_cast<OutT>(val);
                    } else {
                        const int rr = m0 + mt * 16 + (quad << 2) + r;
                        C[(uint32_t)(rr * N + col)] = static_cast<OutT>(val);
                    }
                }
            }
        }
    }
}

// Front: 680 blocks. bx<340 -> query@[off|attn] (NB=3); else value@vproj ->
// head-major f16 v (NB=2).
__global__ __launch_bounds__(256) void gemm_front(
    const float* __restrict__ value, const float* __restrict__ query,
    const bf16* __restrict__ bt_v, const bf16* __restrict__ bt_oa,
    const float* __restrict__ bias_v, const float* __restrict__ bias_oa,
    f16* __restrict__ v_h, bf16* __restrict__ oa_bf)
{
    const int bx = blockIdx.x;
    if (bx < 340)
        gemm_stripe<float, 3, bf16, false>(query, bt_oa, bias_oa, oa_bf, 384,
                                           bx * 64, threadIdx.x);
    else
        gemm_stripe<float, 2, f16, true>(value, bt_v, bias_v, v_h, 256,
                                         (bx - 340) * 64, threadIdx.x);
}

// Back: 340 blocks, NB=2, f32 out.
__global__ __launch_bounds__(256) void gemm_back(
    const bf16* __restrict__ pre, const bf16* __restrict__ bt_out,
    const float* __restrict__ out_b, float* __restrict__ out)
{
    gemm_stripe<bf16, 2, float, false>(pre, bt_out, out_b, out, 256,
                                       blockIdx.x * 64, threadIdx.x);
}

// ---------------------------------------------------------------------------
// Fused softmax + sampling, head-major v, 128B pair-loads.
// Block = 4 queries. Phase 2: wave = 1 query; 8 lanes per head; one load
// fetches the (x0,x1) tap pair (128 B line, fully used); shfl_xor(4) folds
// the two halves. Negative edge offsets land in the 64-B front guard —
// pointer arithmetic MUST be signed (round-8 crash was a uint32_t cast here).
// ---------------------------------------------------------------------------
__global__ __launch_bounds__(256) void msda_sample(
    const f16* __restrict__ v,         // head-major [b][h][5440][32] (guarded)
    const float* __restrict__ ref_pts, // [BS][LEN][4][2]
    const bf16* __restrict__ oa,       // [BS][LEN][384]
    bf16* __restrict__ pre)            // [BS][LEN][256]
{
    const int ib = blockIdx.x;          // [0, 5440)
    const int b  = (ib & 7) >> 1;       // batch per XCD-pair
    const int qg = ((ib >> 3) << 1) + (ib & 1);   // [0, 1360)
    const int q0 = qg * 4;
    const int tid = threadIdx.x;

    __shared__ float  s_ref[32];        // [4 q][8]
    __shared__ float  s_wn[512];        // [4 q][128]
    __shared__ float4 s_pw[544];        // [32 (q,h)][16 pt] stride 17
    __shared__ int2   s_po[544];

    const uint32_t rowbase = (uint32_t)(b * LEN + q0);

    // Phase 0: ref + softmax, one (q,h) per thread
    if (tid < 32) {
        s_ref[tid] = ref_pts[rowbase * 8 + tid];
        const int qi = tid >> 3, h = tid & 7;
        const bf16* ap = oa + (rowbase + qi) * 384 + 256 + h * 16;
        bf16x8 l0 = *(const bf16x8*)ap;
        bf16x8 l1 = *(const bf16x8*)(ap + 8);
        float lg[16];
#pragma unroll
        for (int i = 0; i < 8; ++i) { lg[i] = (float)l0[i]; lg[8 + i] = (float)l1[i]; }
        float m = -1e30f;
#pragma unroll
        for (int i = 0; i < 16; ++i) m = fmaxf(m, lg[i]);
        float s = 0.f;
#pragma unroll
        for (int i = 0; i < 16; ++i) { lg[i] = __expf(lg[i] - m); s += lg[i]; }
        const float inv = 1.f / s;
#pragma unroll
        for (int i = 0; i < 16; ++i) s_wn[qi * 128 + h * 16 + i] = lg[i] * inv;
    }
    __syncthreads();

    // Phase 1: 512 items (q,h,pt), 2 per thread
#pragma unroll
    for (int it = 0; it < 2; ++it) {
        const int item = tid + it * 256;
        const int g  = item >> 4;         // qi*8 + h, 0..31
        const int qi = item >> 7;
        const int h  = (item >> 4) & 7;
        const int pt = item & 15;
        const int l  = pt >> 2;
        const int iw = 64 >> l;
        const int st = (l == 0) ? 0 : ((l == 1) ? 4096 : ((l == 2) ? 5120 : 5376));
        const float fiw = (float)iw;

        bf16x2 ob = *(const bf16x2*)(oa + (rowbase + qi) * 384 + (h * 16 + pt) * 2);
        const float x = s_ref[qi * 8 + l * 2 + 0] * fiw - 0.5f + (float)ob[0];
        const float y = s_ref[qi * 8 + l * 2 + 1] * fiw - 0.5f + (float)ob[1];
        const float x0f = floorf(x), y0f = floorf(y);
        const int x0 = (int)x0f, y0 = (int)y0f;
        const int y1 = y0 + 1;
        const float fx = x - x0f, fy = y - y0f;
        const float wa = s_wn[qi * 128 + h * 16 + pt];

        const float wl = ((x0 >= 0) & (x0 < iw)) ? (1.f - fx) : 0.f;
        const float wr = ((x0 + 1 >= 0) & (x0 + 1 < iw)) ? fx : 0.f;
        const float wy0 = ((y0 >= 0) & (y0 < iw)) ? (1.f - fy) * wa : 0.f;
        const float wy1 = ((y1 >= 0) & (y1 < iw)) ? fy * wa : 0.f;

        const int xp  = min(max(x0, -1), iw - 1);
        const int y0c = min(max(y0, 0), iw - 1);
        const int y1c = min(max(y1, 0), iw - 1);
        const int hb = h * LEN;
        s_pw[g * 17 + pt] = make_float4(wl * wy0, wr * wy0, wl * wy1, wr * wy1);
        s_po[g * 17 + pt] = make_int2((hb + st + y0c * iw + xp) * 64,
                                      (hb + st + y1c * iw + xp) * 64);
    }
    __syncthreads();

    // Phase 2: wave = query; lane: gl = head, c = 0..7 (pair-chunk)
    const int qi = tid >> 6;
    const int lane = tid & 63;
    const int gl = lane >> 3, c = lane & 7;
    const int g = qi * 8 + gl;
    const char* vb = (const char*)v + (size_t)b * (8u * LEN * 64u);
    const int lb = c * 16;                        // SIGNED byte offset part
    const int base = g * 17;
    const bool left = (c < 4);

    float acc[8] = {};
#pragma unroll
    for (int pt = 0; pt < 16; ++pt) {
        const float4 w4 = s_pw[base + pt];
        const int2   o2 = s_po[base + pt];
        const float w0 = left ? w4.x : w4.y;
        const float w1 = left ? w4.z : w4.w;
        f16x8 d0 = *(const f16x8*)(vb + (o2.x + lb));   // signed add: guard handles -64
#pragma unroll
        for (int j = 0; j < 8; ++j) acc[j] = fmaf((float)d0[j], w0, acc[j]);
        f16x8 d1 = *(const f16x8*)(vb + (o2.y + lb));
#pragma unroll
        for (int j = 0; j < 8; ++j) acc[j] = fmaf((float)d1[j], w1, acc[j]);
    }

    // fold x0/x1 halves
#pragma unroll
    for (int j = 0; j < 8; ++j) acc[j] += __shfl_xor(acc[j], 4, 64);

    if (left) {
        bf16x8 o;
#pragma unroll
        for (int j = 0; j < 8; ++j) o[j] = (bf16)acc[j];
        *(bf16x8*)(pre + (rowbase + qi) * 256 + gl * 32 + c * 8) = o;
    }
}

// ---------------------------------------------------------------------------
// Launch: 4 dispatches
// ---------------------------------------------------------------------------
extern "C" void kernel_launch(void* const* d_in, const int* in_sizes, int n_in,
                              void* d_out, int out_size, void* d_ws, size_t ws_size,
                              hipStream_t stream) {
    const float* query   = (const float*)d_in[0];
    const float* ref_pts = (const float*)d_in[1];
    const float* value   = (const float*)d_in[2];
    const float* vproj_w = (const float*)d_in[5];
    const float* vproj_b = (const float*)d_in[6];
    const float* off_w   = (const float*)d_in[7];
    const float* off_b   = (const float*)d_in[8];
    const float* attn_w  = (const float*)d_in[9];
    const float* attn_b  = (const float*)d_in[10];
    const float* out_w   = (const float*)d_in[11];
    const float* out_b   = (const float*)d_in[12];
    float* out = (float*)d_out;

    // workspace layout (64 B guards around head-major v for edge pair-loads)
    char* wsb = (char*)d_ws;
    f16*  v_h    = (f16*)(wsb + 64);                         // ROWS*256 f16
    bf16* oa_bf  = (bf16*)(wsb + 64 + (size_t)ROWS * 512 + 64);  // ROWS*384
    bf16* pre_bf = oa_bf  + (size_t)ROWS * 384;              // ROWS*256
    bf16* bt_v   = pre_bf + (size_t)ROWS * 256;              // 256*256 (frag order)
    bf16* bt_oa  = bt_v   + 256 * 256;                       // 384*256 (frag order)
    bf16* bt_out = bt_oa  + 384 * 256;                       // 256*256 (frag order)
    float* bias_oa = (float*)(bt_out + 256 * 256);           // 384 f32

    dim3 blk(256);

    prep_weights<<<dim3(57), blk, 0, stream>>>(vproj_w, off_w, attn_w, out_w,
                                               off_b, attn_b, bt_v, bt_oa, bt_out, bias_oa);

    gemm_front<<<dim3(680), blk, 0, stream>>>(value, query, bt_v, bt_oa,
                                              vproj_b, bias_oa, v_h, oa_bf);

    msda_sample<<<dim3(5440), blk, 0, stream>>>(v_h, ref_pts, oa_bf, pre_bf);

    gemm_back<<<dim3(340), blk, 0, stream>>>(pre_bf, bt_out, out_b, out);
}